// Round 1
// baseline (1003.980 us; speedup 1.0000x reference)
//
#include <hip/hip_runtime.h>

// Problem constants (from reference): B=32, N=200000, RESOLUTIONS=(8,16,32,64)
static constexpr int B_   = 32;
static constexpr int N_   = 200000;
static constexpr int VOXB = 512 + 4096 + 32768 + 262144;   // 299520 voxels per batch
static constexpr int OFF8  = 0;
static constexpr int OFF16 = 512;
static constexpr int OFF32 = 512 + 4096;                   // 4608
static constexpr int OFF64 = 512 + 4096 + 32768;           // 37376

// Scatter unscaled point coords into the res-64 region of d_out.
// Each thread handles 4 points (48 B = 3x float4 loads, 16B-aligned).
__global__ void __launch_bounds__(256) scatter64_k(const float* __restrict__ pts,
                                                   float* __restrict__ out) {
    int tid = blockIdx.x * 256 + threadIdx.x;              // quad index
    if (tid >= (B_ * N_) / 4) return;
    const float4* p4 = reinterpret_cast<const float4*>(pts) + tid * 3;
    float4 q0 = p4[0], q1 = p4[1], q2 = p4[2];
    float px[4] = {q0.x, q0.w, q1.z, q2.y};
    float py[4] = {q0.y, q1.x, q1.w, q2.z};
    float pz[4] = {q0.z, q1.y, q2.x, q2.w};
    int b = tid / (N_ / 4);                                // N%4==0: quad never crosses batch
    float* base = out + (b * VOXB + OFF64) * 3;
    #pragma unroll
    for (int k = 0; k < 4; ++k) {
        float x = px[k], y = py[k], z = pz[k];
        // matches reference: (p * res) f32-mul then trunc; p in [0,1) so ix<=63
        int ix = (int)(x * 64.0f), iy = (int)(y * 64.0f), iz = (int)(z * 64.0f);
        int flat = (ix << 12) + (iy << 6) + iz;
        float* d = base + flat * 3;
        atomicAdd(d,     x);
        atomicAdd(d + 1, y);
        atomicAdd(d + 2, z);
    }
}

// Downsample (2R)^3 -> R^3 per batch. Reads the UNSCALED fine grid, writes the
// unscaled 8-child sum to the coarse region, and rescales the fine region
// in place by its per-(batch,level) scale (fusing the epilogue scale).
template<int LOUT>  // log2 of output resolution
__global__ void __launch_bounds__(256) downsample_k(float* __restrict__ out,
                                                    const float* __restrict__ rm,
                                                    int inOff, int outOff, int rmIdxIn) {
    constexpr int R  = 1 << LOUT;
    constexpr int NV = R * R * R;
    int tid = blockIdx.x * 256 + threadIdx.x;
    if (tid >= B_ * NV) return;
    int b = tid >> (3 * LOUT);
    int v = tid & (NV - 1);
    int z = v & (R - 1);
    int y = (v >> LOUT) & (R - 1);
    int x = v >> (2 * LOUT);
    float s = rm[b * 4 + rmIdxIn];                          // scale of the FINE level
    float* bin  = out + (b * VOXB + inOff) * 3;
    float* bout = out + (b * VOXB + outOff) * 3;
    constexpr int R2 = 2 * R;
    float sx = 0.f, sy = 0.f, sz = 0.f;
    #pragma unroll
    for (int dx = 0; dx < 2; ++dx)
      #pragma unroll
      for (int dy = 0; dy < 2; ++dy) {
        int cf = ((2 * x + dx) * R2 + (2 * y + dy)) * R2 + 2 * z;
        float* cp = bin + cf * 3;                           // 2 z-children: 6 contiguous floats
        float v0 = cp[0], v1 = cp[1], v2 = cp[2], v3 = cp[3], v4 = cp[4], v5 = cp[5];
        sx += v0 + v3; sy += v1 + v4; sz += v2 + v5;
        cp[0] = v0 * s; cp[1] = v1 * s; cp[2] = v2 * s;
        cp[3] = v3 * s; cp[4] = v4 * s; cp[5] = v5 * s;
      }
    float* op = bout + v * 3;
    op[0] = sx; op[1] = sy; op[2] = sz;
}

// Final: scale the res-8 region in place.
__global__ void __launch_bounds__(256) scale8_k(float* __restrict__ out,
                                                const float* __restrict__ rm) {
    int tid = blockIdx.x * 256 + threadIdx.x;
    if (tid >= B_ * 512) return;
    int b = tid >> 9, v = tid & 511;
    float s = rm[b * 4 + 0];
    float* p = out + (b * VOXB + OFF8 + v) * 3;
    p[0] *= s; p[1] *= s; p[2] *= s;
}

extern "C" void kernel_launch(void* const* d_in, const int* in_sizes, int n_in,
                              void* d_out, int out_size, void* d_ws, size_t ws_size,
                              hipStream_t stream) {
    const float* pts = (const float*)d_in[0];   // [B, N, 3] f32
    const float* rm  = (const float*)d_in[1];   // [B, 4, 1] f32
    float* out = (float*)d_out;                 // [B, 299520, 3] f32

    // d_out is poisoned / holds stale data between replays — zero it every call.
    hipMemsetAsync(d_out, 0, (size_t)out_size * sizeof(float), stream);

    scatter64_k<<<(B_ * N_ / 4 + 255) / 256, 256, 0, stream>>>(pts, out);
    // 64 -> 32 (scales res-64 region by rm[:,3]), 32 -> 16, 16 -> 8, then scale res-8.
    downsample_k<5><<<(B_ * 32768 + 255) / 256, 256, 0, stream>>>(out, rm, OFF64, OFF32, 3);
    downsample_k<4><<<(B_ * 4096  + 255) / 256, 256, 0, stream>>>(out, rm, OFF32, OFF16, 2);
    downsample_k<3><<<(B_ * 512   + 255) / 256, 256, 0, stream>>>(out, rm, OFF16, OFF8,  1);
    scale8_k<<<(B_ * 512 + 255) / 256, 256, 0, stream>>>(out, rm);
}